// Round 9
// baseline (109.314 us; speedup 1.0000x reference)
//
#include <hip/hip_runtime.h>
#include <math.h>

#define N 1024
#define D 512
#define NC 16

static constexpr float THRESH    = 0.5f;
static constexpr float MARGIN    = 0.1f;
static constexpr float SCALE_POS = 0.05f;
static constexpr float SCALE_NEG = 0.002f;
static constexpr float EPS_      = 1e-5f;

typedef __bf16 bf16x8 __attribute__((ext_vector_type(8)));
typedef float  f32x4  __attribute__((ext_vector_type(4)));

__device__ __forceinline__ bf16x8 cvt8(const float4 a, const float4 b) {
    bf16x8 r;
    r[0] = (__bf16)a.x; r[1] = (__bf16)a.y; r[2] = (__bf16)a.z; r[3] = (__bf16)a.w;
    r[4] = (__bf16)b.x; r[5] = (__bf16)b.y; r[6] = (__bf16)b.z; r[7] = (__bf16)b.w;
    return r;
}

// ---------------------------------------------------------------------------
// Kernel 1 (R7-proven): fused fp32->bf16 + MFMA GEMM via phased LDS staging
// + label pack + d_out zeroing (kernel boundary publishes the zero).
// ---------------------------------------------------------------------------
__global__ __launch_bounds__(256) void gemm_lds(const float* __restrict__ F,
                                                const int* __restrict__ labels,
                                                float* __restrict__ S,
                                                unsigned* __restrict__ mask,
                                                float* __restrict__ out) {
    __shared__ __bf16 Asm[64][72];
    __shared__ __bf16 Bsm[64][72];

    const int tid = threadIdx.x;
    const int bx = blockIdx.x, by = blockIdx.y;
    const int bl = by * 16 + bx;

    if (bl == 0 && tid == 0) out[0] = 0.0f;

    if (tid < 4) {
        const int row = bl * 4 + tid;
        const int4* lp = (const int4*)(labels + row * NC);
        unsigned m = 0;
        #pragma unroll
        for (int q = 0; q < 4; ++q) {
            int4 l4 = lp[q];
            if (l4.x == 1) m |= 1u << (q * 4 + 0);
            if (l4.y == 1) m |= 1u << (q * 4 + 1);
            if (l4.z == 1) m |= 1u << (q * 4 + 2);
            if (l4.w == 1) m |= 1u << (q * 4 + 3);
        }
        mask[row] = m;
    }

    const int wave = tid >> 6;
    const int lane = tid & 63;
    const int row0 = by * 64;
    const int col0 = bx * 64;
    const int lr = lane & 15;
    const int lk = (lane >> 4) * 8;

    const int sr = tid >> 2;
    const int sk = (tid & 3) * 16;
    const float* Fa = F + (size_t)(row0 + sr) * D + sk;
    const float* Fb = F + (size_t)(col0 + sr) * D + sk;

    f32x4 acc0 = {}, acc1 = {}, acc2 = {}, acc3 = {};

    for (int kp = 0; kp < D; kp += 64) {
        const float4* qa = (const float4*)(Fa + kp);
        const float4* qb = (const float4*)(Fb + kp);
        float4 a0 = qa[0], a1 = qa[1], a2 = qa[2], a3 = qa[3];
        float4 b0 = qb[0], b1 = qb[1], b2 = qb[2], b3 = qb[3];
        *(bf16x8*)(&Asm[sr][sk])     = cvt8(a0, a1);
        *(bf16x8*)(&Asm[sr][sk + 8]) = cvt8(a2, a3);
        *(bf16x8*)(&Bsm[sr][sk])     = cvt8(b0, b1);
        *(bf16x8*)(&Bsm[sr][sk + 8]) = cvt8(b2, b3);
        __syncthreads();

        #pragma unroll
        for (int kk = 0; kk < 64; kk += 32) {
            bf16x8 av  = *(const bf16x8*)(&Asm[wave * 16 + lr][kk + lk]);
            bf16x8 bv0 = *(const bf16x8*)(&Bsm[lr     ][kk + lk]);
            bf16x8 bv1 = *(const bf16x8*)(&Bsm[lr + 16][kk + lk]);
            bf16x8 bv2 = *(const bf16x8*)(&Bsm[lr + 32][kk + lk]);
            bf16x8 bv3 = *(const bf16x8*)(&Bsm[lr + 48][kk + lk]);
            acc0 = __builtin_amdgcn_mfma_f32_16x16x32_bf16(av, bv0, acc0, 0, 0, 0);
            acc1 = __builtin_amdgcn_mfma_f32_16x16x32_bf16(av, bv1, acc1, 0, 0, 0);
            acc2 = __builtin_amdgcn_mfma_f32_16x16x32_bf16(av, bv2, acc2, 0, 0, 0);
            acc3 = __builtin_amdgcn_mfma_f32_16x16x32_bf16(av, bv3, acc3, 0, 0, 0);
        }
        __syncthreads();
    }

    // C/D: col = lane&15, row = (lane>>4)*4 + reg. Diagonal pinned to 1.0f
    // (fp32 self-sim is excluded by the 1-eps test; bf16 rounding must not
    // let it sneak back in).
    const int r0 = row0 + wave * 16 + (lane >> 4) * 4;
    const int c0 = col0 + lr;
    #pragma unroll
    for (int r = 0; r < 4; ++r) {
        const int rr = r0 + r;
        float* Sr = S + (size_t)rr * N + c0;
        Sr[0]  = (rr == c0     ) ? 1.0f : acc0[r];
        Sr[16] = (rr == c0 + 16) ? 1.0f : acc1[r];
        Sr[32] = (rr == c0 + 32) ? 1.0f : acc2[r];
        Sr[48] = (rr == c0 + 48) ? 1.0f : acc3[r];
    }
}

// ---------------------------------------------------------------------------
// Kernel 2: MS reduction, 256 blocks x 4 rows. Wave w owns row 4*blockIdx+w
// ALONE (all 16 classes in-wave, no cross-wave coupling). Each wave's mk[]
// spans all 1024 masks -> global anchor total free. ONE scaled atomicAdd per
// block -> 256 same-address atomics (R8 lesson: 1024 cost ~+9us; /4 here).
// ---------------------------------------------------------------------------
__global__ __launch_bounds__(256) void ms_reduce256(const float* __restrict__ S,
                                                    const unsigned* __restrict__ mask,
                                                    float* __restrict__ out) {
    const int tid  = threadIdx.x;
    const int lane = tid & 63;
    const int wave = tid >> 6;
    const int i    = blockIdx.x * 4 + wave;

    float    s[16];
    unsigned mk[16];
    {
        const float4* Srow = (const float4*)(S + (size_t)i * N);
        const uint4*  Mrow = (const uint4*)mask;
        #pragma unroll
        for (int q = 0; q < 4; ++q) {
            float4 v = Srow[lane * 4 + q];
            uint4  m = Mrow[lane * 4 + q];
            s[q * 4 + 0] = v.x; s[q * 4 + 1] = v.y;
            s[q * 4 + 2] = v.z; s[q * 4 + 3] = v.w;
            mk[q * 4 + 0] = m.x; mk[q * 4 + 1] = m.y;
            mk[q * 4 + 2] = m.z; mk[q * 4 + 3] = m.w;
        }
    }

    // ---- global anchor count (free: mk spans all rows) ----
    int cnt = 0;
    #pragma unroll
    for (int u = 0; u < 16; ++u) cnt += __popc(mk[u]);

    // ---- pass 1: per-class min_pos / max_neg (16 classes in-wave) ----
    float mn[16], mx[16];
    #pragma unroll
    for (int c = 0; c < 16; ++c) { mn[c] = INFINITY; mx[c] = -INFINITY; }
    #pragma unroll
    for (int u = 0; u < 16; ++u) {
        const float sv = s[u];
        const bool ok1 = sv < 1.0f - EPS_;
        #pragma unroll
        for (int c = 0; c < 16; ++c) {
            const bool pos = (mk[u] >> c) & 1u;
            mn[c] = fminf(mn[c], (pos && ok1) ? sv : INFINITY);
            mx[c] = fmaxf(mx[c], pos ? -INFINITY : sv);
        }
    }
    #pragma unroll
    for (int off = 32; off; off >>= 1) {
        cnt += __shfl_xor(cnt, off, 64);
        #pragma unroll
        for (int c = 0; c < 16; ++c) {
            mn[c] = fminf(mn[c], __shfl_xor(mn[c], off, 64));
            mx[c] = fmaxf(mx[c], __shfl_xor(mx[c], off, 64));
        }
    }
    #pragma unroll
    for (int c = 0; c < 16; ++c) {
        mn[c] = (mn[c] < INFINITY) ? mn[c] : -INFINITY;   // min_pos_eff
    }

    // ---- pass 2: selected exp sums ----
    float ps[16], ns[16];
    #pragma unroll
    for (int c = 0; c < 16; ++c) { ps[c] = 0.0f; ns[c] = 0.0f; }
    #pragma unroll
    for (int u = 0; u < 16; ++u) {
        const float sv = s[u];
        const float ep = __expf(-SCALE_POS * (sv - THRESH));
        const float en = __expf( SCALE_NEG * (sv - THRESH));
        const bool ok1 = sv < 1.0f - EPS_;
        const float sm = sv - MARGIN;
        const float sp = sv + MARGIN;
        #pragma unroll
        for (int c = 0; c < 16; ++c) {
            const bool pos  = (mk[u] >> c) & 1u;
            const bool psel = pos && ok1 && (sm < mx[c]);
            const bool nsel = (!pos) && (sp > mn[c]);
            ps[c] += psel ? ep : 0.0f;
            ns[c] += nsel ? en : 0.0f;
        }
    }
    #pragma unroll
    for (int off = 32; off; off >>= 1) {
        #pragma unroll
        for (int c = 0; c < 16; ++c) {
            ps[c] += __shfl_xor(ps[c], off, 64);
            ns[c] += __shfl_xor(ns[c], off, 64);
        }
    }

    // ---- per-wave (per-row) loss, block combine, ONE scaled atomic ----
    __shared__ double part[4];
    __shared__ int    s_cnt;
    if (lane == 0) {
        const unsigned am = mask[i];
        double lc = 0.0;
        #pragma unroll
        for (int c = 0; c < 16; ++c) {
            const bool anchor = (am >> c) & 1u;
            if (anchor && ps[c] > 0.0f && ns[c] > 0.0f) {
                lc += (double)(log1pf(ps[c]) * (1.0f / SCALE_POS))
                    + (double)(log1pf(ns[c]) * (1.0f / SCALE_NEG));
            }
        }
        part[wave] = lc;
        if (wave == 0) s_cnt = cnt;
    }
    __syncthreads();
    if (tid == 0) {
        const double lc = part[0] + part[1] + part[2] + part[3];
        const int    T  = s_cnt;
        if (T > 0 && lc != 0.0) {
            atomicAdd(out, (float)(lc / (double)T));
        }
    }
}

// ---------------------------------------------------------------------------
extern "C" void kernel_launch(void* const* d_in, const int* in_sizes, int n_in,
                              void* d_out, int out_size, void* d_ws, size_t ws_size,
                              hipStream_t stream) {
    (void)in_sizes; (void)n_in; (void)out_size; (void)ws_size;
    const float* feats  = (const float*)d_in[0];
    const int*   labels = (const int*)d_in[1];
    float*       out    = (float*)d_out;

    char* ws = (char*)d_ws;
    float*    sim  = (float*)ws;
    unsigned* mask = (unsigned*)(ws + (size_t)N * N * 4);

    dim3 gg(N / 64, N / 64);
    gemm_lds<<<gg, 256, 0, stream>>>(feats, labels, sim, mask, out);
    ms_reduce256<<<N / 4, 256, 0, stream>>>(sim, mask, out);
}

// Round 10
// 85.624 us; speedup vs baseline: 1.2767x; 1.2767x over previous
//
#include <hip/hip_runtime.h>
#include <math.h>

#define N 1024
#define D 512
#define NC 16

static constexpr float THRESH    = 0.5f;
static constexpr float MARGIN    = 0.1f;
static constexpr float SCALE_POS = 0.05f;
static constexpr float SCALE_NEG = 0.002f;
static constexpr float EPS_      = 1e-5f;

typedef __bf16 bf16x8 __attribute__((ext_vector_type(8)));
typedef float  f32x4  __attribute__((ext_vector_type(4)));

__device__ __forceinline__ bf16x8 cvt8(const float4 a, const float4 b) {
    bf16x8 r;
    r[0] = (__bf16)a.x; r[1] = (__bf16)a.y; r[2] = (__bf16)a.z; r[3] = (__bf16)a.w;
    r[4] = (__bf16)b.x; r[5] = (__bf16)b.y; r[6] = (__bf16)b.z; r[7] = (__bf16)b.w;
    return r;
}

// ---------------------------------------------------------------------------
// Kernel 1: fused fp32->bf16 + MFMA GEMM via phased LDS staging + label pack.
// Convert ONCE per 64-wide K phase into LDS (off the MFMA critical path),
// then m97-style ds_read_b128 frags. LDS rows padded to 72 bf16 (144 B).
// Diagonal pinned to 1.0f (fp32 self-sim is excluded by the 1-eps test; bf16
// rounding must not let it sneak back in).  [R7-proven: 85.8us total]
// ---------------------------------------------------------------------------
__global__ __launch_bounds__(256) void gemm_lds(const float* __restrict__ F,
                                                const int* __restrict__ labels,
                                                float* __restrict__ S,
                                                unsigned* __restrict__ mask) {
    __shared__ __bf16 Asm[64][72];
    __shared__ __bf16 Bsm[64][72];

    const int tid = threadIdx.x;
    const int bx = blockIdx.x, by = blockIdx.y;
    const int bl = by * 16 + bx;

    // ---- label pack: block bl packs rows 4bl..4bl+3 ----
    if (tid < 4) {
        const int row = bl * 4 + tid;
        const int4* lp = (const int4*)(labels + row * NC);
        unsigned m = 0;
        #pragma unroll
        for (int q = 0; q < 4; ++q) {
            int4 l4 = lp[q];
            if (l4.x == 1) m |= 1u << (q * 4 + 0);
            if (l4.y == 1) m |= 1u << (q * 4 + 1);
            if (l4.z == 1) m |= 1u << (q * 4 + 2);
            if (l4.w == 1) m |= 1u << (q * 4 + 3);
        }
        mask[row] = m;
    }

    const int wave = tid >> 6;
    const int lane = tid & 63;
    const int row0 = by * 64;
    const int col0 = bx * 64;
    const int lr = lane & 15;         // m (A) / n (B) within 16
    const int lk = (lane >> 4) * 8;   // k sub-offset

    const int sr = tid >> 2;
    const int sk = (tid & 3) * 16;
    const float* Fa = F + (size_t)(row0 + sr) * D + sk;
    const float* Fb = F + (size_t)(col0 + sr) * D + sk;

    f32x4 acc0 = {}, acc1 = {}, acc2 = {}, acc3 = {};

    for (int kp = 0; kp < D; kp += 64) {
        const float4* qa = (const float4*)(Fa + kp);
        const float4* qb = (const float4*)(Fb + kp);
        float4 a0 = qa[0], a1 = qa[1], a2 = qa[2], a3 = qa[3];
        float4 b0 = qb[0], b1 = qb[1], b2 = qb[2], b3 = qb[3];
        *(bf16x8*)(&Asm[sr][sk])     = cvt8(a0, a1);
        *(bf16x8*)(&Asm[sr][sk + 8]) = cvt8(a2, a3);
        *(bf16x8*)(&Bsm[sr][sk])     = cvt8(b0, b1);
        *(bf16x8*)(&Bsm[sr][sk + 8]) = cvt8(b2, b3);
        __syncthreads();

        #pragma unroll
        for (int kk = 0; kk < 64; kk += 32) {
            bf16x8 av  = *(const bf16x8*)(&Asm[wave * 16 + lr][kk + lk]);
            bf16x8 bv0 = *(const bf16x8*)(&Bsm[lr     ][kk + lk]);
            bf16x8 bv1 = *(const bf16x8*)(&Bsm[lr + 16][kk + lk]);
            bf16x8 bv2 = *(const bf16x8*)(&Bsm[lr + 32][kk + lk]);
            bf16x8 bv3 = *(const bf16x8*)(&Bsm[lr + 48][kk + lk]);
            acc0 = __builtin_amdgcn_mfma_f32_16x16x32_bf16(av, bv0, acc0, 0, 0, 0);
            acc1 = __builtin_amdgcn_mfma_f32_16x16x32_bf16(av, bv1, acc1, 0, 0, 0);
            acc2 = __builtin_amdgcn_mfma_f32_16x16x32_bf16(av, bv2, acc2, 0, 0, 0);
            acc3 = __builtin_amdgcn_mfma_f32_16x16x32_bf16(av, bv3, acc3, 0, 0, 0);
        }
        __syncthreads();
    }

    // C/D layout: col = lane&15, row = (lane>>4)*4 + reg
    const int r0 = row0 + wave * 16 + (lane >> 4) * 4;
    const int c0 = col0 + lr;
    #pragma unroll
    for (int r = 0; r < 4; ++r) {
        const int rr = r0 + r;
        float* Sr = S + (size_t)rr * N + c0;
        Sr[0]  = (rr == c0     ) ? 1.0f : acc0[r];
        Sr[16] = (rr == c0 + 16) ? 1.0f : acc1[r];
        Sr[32] = (rr == c0 + 32) ? 1.0f : acc2[r];
        Sr[48] = (rr == c0 + 48) ? 1.0f : acc3[r];
    }
}

// ---------------------------------------------------------------------------
// Kernel 2: per-row MS reduction. Block = row i (1024 blocks -> 4 waves/SIMD
// machine-wide; R9 lesson: shrinking the grid to 256 blocks collapses TLP
// and costs +21us). Wave w owns classes 4w..4w+3 over all 1024 j. Plain
// store to own slot; no cross-block atomics/fences (R3/R5/R8 lessons:
// completion tails cost +4..25us).
// ---------------------------------------------------------------------------
__global__ __launch_bounds__(256) void ms_reduce(const float* __restrict__ S,
                                                 const unsigned* __restrict__ mask,
                                                 double* __restrict__ partials) {
    const int i    = blockIdx.x;
    const int tid  = threadIdx.x;
    const int lane = tid & 63;
    const int wave = tid >> 6;
    const int cbase = wave * 4;

    float    s[16];
    unsigned mk[16];
    {
        const float4* Srow = (const float4*)(S + (size_t)i * N);
        const uint4*  Mrow = (const uint4*)mask;
        #pragma unroll
        for (int q = 0; q < 4; ++q) {
            float4 v = Srow[lane * 4 + q];
            uint4  m = Mrow[lane * 4 + q];
            s[q * 4 + 0] = v.x; s[q * 4 + 1] = v.y;
            s[q * 4 + 2] = v.z; s[q * 4 + 3] = v.w;
            mk[q * 4 + 0] = m.x; mk[q * 4 + 1] = m.y;
            mk[q * 4 + 2] = m.z; mk[q * 4 + 3] = m.w;
        }
    }

    // ---- pass 1: per-class min_pos / max_neg ----
    float mn[4] = {INFINITY, INFINITY, INFINITY, INFINITY};
    float mx[4] = {-INFINITY, -INFINITY, -INFINITY, -INFINITY};
    #pragma unroll
    for (int u = 0; u < 16; ++u) {
        const float sv = s[u];
        const bool ok1 = sv < 1.0f - EPS_;
        #pragma unroll
        for (int cl = 0; cl < 4; ++cl) {
            const bool pos = (mk[u] >> (cbase + cl)) & 1u;
            mn[cl] = fminf(mn[cl], (pos && ok1) ? sv : INFINITY);
            mx[cl] = fmaxf(mx[cl], pos ? -INFINITY : sv);
        }
    }
    #pragma unroll
    for (int off = 32; off; off >>= 1) {
        #pragma unroll
        for (int cl = 0; cl < 4; ++cl) {
            mn[cl] = fminf(mn[cl], __shfl_xor(mn[cl], off, 64));
            mx[cl] = fmaxf(mx[cl], __shfl_xor(mx[cl], off, 64));
        }
    }
    float mpe[4], mxn[4];
    #pragma unroll
    for (int cl = 0; cl < 4; ++cl) {
        mpe[cl] = (mn[cl] < INFINITY) ? mn[cl] : -INFINITY;
        mxn[cl] = mx[cl];
    }

    // ---- pass 2: selected exp sums ----
    float ps[4] = {}, ns[4] = {};
    #pragma unroll
    for (int u = 0; u < 16; ++u) {
        const float sv = s[u];
        const float ep = __expf(-SCALE_POS * (sv - THRESH));
        const float en = __expf( SCALE_NEG * (sv - THRESH));
        const bool ok1 = sv < 1.0f - EPS_;
        const float sm = sv - MARGIN;
        const float sp = sv + MARGIN;
        #pragma unroll
        for (int cl = 0; cl < 4; ++cl) {
            const bool pos  = (mk[u] >> (cbase + cl)) & 1u;
            const bool psel = pos && ok1 && (sm < mxn[cl]);
            const bool nsel = (!pos) && (sp > mpe[cl]);
            ps[cl] += psel ? ep : 0.0f;
            ns[cl] += nsel ? en : 0.0f;
        }
    }
    #pragma unroll
    for (int off = 32; off; off >>= 1) {
        #pragma unroll
        for (int cl = 0; cl < 4; ++cl) {
            ps[cl] += __shfl_xor(ps[cl], off, 64);
            ns[cl] += __shfl_xor(ns[cl], off, 64);
        }
    }

    // ---- per-wave loss, block combine in LDS, ONE plain store per block ----
    __shared__ double part[4];
    if (lane == 0) {
        const unsigned am = mask[i];
        double lc = 0.0;
        #pragma unroll
        for (int cl = 0; cl < 4; ++cl) {
            const bool anchor = (am >> (cbase + cl)) & 1u;
            if (anchor && ps[cl] > 0.0f && ns[cl] > 0.0f) {
                lc += (double)(log1pf(ps[cl]) * (1.0f / SCALE_POS))
                    + (double)(log1pf(ns[cl]) * (1.0f / SCALE_NEG));
            }
        }
        part[wave] = lc;
    }
    __syncthreads();
    if (tid == 0) {
        partials[i] = part[0] + part[1] + part[2] + part[3];
    }
}

// ---------------------------------------------------------------------------
// Kernel 3: single-block finalize — sum 1024 partials + anchor count from mask
// ---------------------------------------------------------------------------
__global__ __launch_bounds__(256) void finalize(const double* __restrict__ partials,
                                                const unsigned* __restrict__ mask,
                                                float* __restrict__ out) {
    const int tid  = threadIdx.x;
    const int lane = tid & 63;
    const int wave = tid >> 6;

    double s = 0.0;
    int cnt = 0;
    #pragma unroll
    for (int q = 0; q < 4; ++q) {
        s   += partials[tid * 4 + q];
        cnt += __popc(mask[tid * 4 + q]);
    }
    #pragma unroll
    for (int off = 32; off; off >>= 1) {
        s   += __shfl_xor(s, off, 64);
        cnt += __shfl_xor(cnt, off, 64);
    }
    __shared__ double sred[4];
    __shared__ int    cred[4];
    if (lane == 0) { sred[wave] = s; cred[wave] = cnt; }
    __syncthreads();
    if (tid == 0) {
        const double L = sred[0] + sred[1] + sred[2] + sred[3];
        const int    T = cred[0] + cred[1] + cred[2] + cred[3];
        out[0] = (T > 0) ? (float)(L / (double)T) : 0.0f;
    }
}

// ---------------------------------------------------------------------------
extern "C" void kernel_launch(void* const* d_in, const int* in_sizes, int n_in,
                              void* d_out, int out_size, void* d_ws, size_t ws_size,
                              hipStream_t stream) {
    (void)in_sizes; (void)n_in; (void)out_size; (void)ws_size;
    const float* feats  = (const float*)d_in[0];
    const int*   labels = (const int*)d_in[1];
    float*       out    = (float*)d_out;

    // ws layout: [0,4MB) sim | +4KB mask | 1024 doubles partials
    char* ws = (char*)d_ws;
    float*    sim      = (float*)ws;
    unsigned* mask     = (unsigned*)(ws + (size_t)N * N * 4);
    double*   partials = (double*)(ws + (size_t)N * N * 4 + 4096);

    dim3 gg(N / 64, N / 64);
    gemm_lds<<<gg, 256, 0, stream>>>(feats, labels, sim, mask);
    ms_reduce<<<N, 256, 0, stream>>>(sim, mask, partials);
    finalize<<<1, 256, 0, stream>>>(partials, mask, out);
}